// Round 1
// baseline (668.859 us; speedup 1.0000x reference)
//
#include <hip/hip_runtime.h>
#include <stdint.h>

// Problem constants (fixed by reference setup_inputs)
#define BB 32
#define NN 131072            // 2^17
#define BN (BB * NN)         // 4,194,304 = 2^22
#define TT 32768             // NUM_POINTS_TARGET
#define CELL 0.05f
#define HBITS 23
#define HSIZE (1 << HBITS)   // 8,388,608 slots
#define HMASK (HSIZE - 1)

// Output layout in d_out (floats), in return order:
// y_sel [32,32768,3], idx_out [32,32768,2], mask_sel [32,32768],
// ul_idx [BN], ul_idx_inv [BN]
#define Y_OFF   0
#define IDX_OFF (BB * TT * 3)                    // 3,145,728
#define MSK_OFF (IDX_OFF + BB * TT * 2)          // 5,242,880
#define ULI_OFF (MSK_OFF + BB * TT)              // 6,291,456
#define ULV_OFF (ULI_OFF + BN)                   // 10,485,760

#define SCAN_TPB 256
#define SCAN_EPT 16
#define SCAN_EPB (SCAN_TPB * SCAN_EPT)           // 4096
#define SCAN_NBLK (BN / SCAN_EPB)                // 1024

__global__ void k_init(int* scal) {
    scal[0] = 0x7FFFFFFF;  // min
    scal[1] = 0x80000000;  // max
    scal[2] = 0;           // total uniques
}

// Global min/max over all 3*BN quantized coords
__global__ void k_minmax(const float* __restrict__ x, int* scal) {
    int tid = blockIdx.x * blockDim.x + threadIdx.x;
    int stride = gridDim.x * blockDim.x;
    int lmin = 0x7FFFFFFF, lmax = (int)0x80000000;
    for (int i = tid; i < 3 * BN; i += stride) {
        int g = (int)rintf(x[i] / CELL);   // round half-to-even like jnp.round
        lmin = min(lmin, g);
        lmax = max(lmax, g);
    }
    for (int off = 32; off > 0; off >>= 1) {
        lmin = min(lmin, __shfl_down(lmin, off));
        lmax = max(lmax, __shfl_down(lmax, off));
    }
    if ((threadIdx.x & 63) == 0) {
        atomicMin(&scal[0], lmin);
        atomicMax(&scal[1], lmax);
    }
}

// Compute voxel key per point, insert into hash (atomicMin of flat index)
__global__ void k_insert(const float* __restrict__ x, const int* __restrict__ scal,
                         int* __restrict__ hkeys, int* __restrict__ hmin,
                         int* __restrict__ slotArr) {
    int i = blockIdx.x * blockDim.x + threadIdx.x;
    if (i >= BN) return;
    int ming = scal[0];
    int gs = scal[1] - ming + 2;
    int g0 = (int)rintf(x[3 * i + 0] / CELL) - ming;
    int g1 = (int)rintf(x[3 * i + 1] / CELL) - ming;
    int g2 = (int)rintf(x[3 * i + 2] / CELL) - ming;
    int b = i >> 17;  // i / NN
    int key = gs * (gs * g0 + g1) + g2 + gs * gs * gs * b;  // < ~4.5e8, fits int32
    uint32_t s = ((uint32_t)key * 2654435761u) >> (32 - HBITS);
    for (;;) {
        int k = hkeys[s];
        if (k == key) break;
        if (k == -1) {
            int old = atomicCAS(&hkeys[s], -1, key);
            if (old == -1 || old == key) break;
        }
        s = (s + 1) & HMASK;
    }
    atomicMin(&hmin[s], i);
    slotArr[i] = (int)s;
}

// Scan pass A: resolve first-occurrence position per point; block partial sums of flags
__global__ void k_scanA(const int* __restrict__ slotArr, const int* __restrict__ hmin,
                        int* __restrict__ pfirst, int* __restrict__ bsums) {
    int t = threadIdx.x;
    int base = blockIdx.x * SCAN_EPB + t * SCAN_EPT;
    int s = 0;
    for (int e = 0; e < SCAN_EPT; e++) {
        int i = base + e;
        int p = hmin[slotArr[i]];
        pfirst[i] = p;
        s += (p == i);
    }
    __shared__ int sh[SCAN_TPB];
    sh[t] = s;
    __syncthreads();
    for (int off = SCAN_TPB / 2; off > 0; off >>= 1) {
        if (t < off) sh[t] += sh[t + off];
        __syncthreads();
    }
    if (t == 0) bsums[blockIdx.x] = sh[0];
}

// Scan pass B: exclusive scan of 1024 block sums; store grand total
__global__ void k_scanB(int* __restrict__ bsums, int* __restrict__ scal, int nb) {
    __shared__ int sh[1024];
    int t = threadIdx.x;
    int v = (t < nb) ? bsums[t] : 0;
    sh[t] = v;
    __syncthreads();
    for (int off = 1; off < 1024; off <<= 1) {
        int add = (t >= off) ? sh[t - off] : 0;
        __syncthreads();
        sh[t] += add;
        __syncthreads();
    }
    if (t < nb) bsums[t] = sh[t] - v;       // exclusive
    if (t == nb - 1) scal[2] = sh[t];       // total uniques U
}

// Scan pass C: write exclusive scan per element; scatter ul_idx_inv[rank] = pos
__global__ void k_scanC(const int* __restrict__ pfirst, const int* __restrict__ bsums,
                        int* __restrict__ scanArr, float* __restrict__ ulinv) {
    int t = threadIdx.x;
    int base = blockIdx.x * SCAN_EPB + t * SCAN_EPT;
    int flags[SCAN_EPT];
    int s = 0;
    for (int e = 0; e < SCAN_EPT; e++) {
        int i = base + e;
        int p = pfirst[i];
        flags[e] = (p == i) ? 1 : 0;
        s += flags[e];
    }
    __shared__ int sh[SCAN_TPB];
    sh[t] = s;
    __syncthreads();
    int v = s;
    for (int off = 1; off < SCAN_TPB; off <<= 1) {
        int add = (t >= off) ? sh[t - off] : 0;
        __syncthreads();
        sh[t] += add;
        __syncthreads();
    }
    int prefix = bsums[blockIdx.x] + sh[t] - v;  // exclusive prefix for this thread
    for (int e = 0; e < SCAN_EPT; e++) {
        int i = base + e;
        scanArr[i] = prefix;
        if (flags[e]) ulinv[prefix] = (float)i;
        prefix += flags[e];
    }
}

// ul_idx[i] = appearance rank of i's voxel = scan at its first-occurrence pos;
// pad ul_idx_inv tail with sentinel BN
__global__ void k_final(const int* __restrict__ pfirst, const int* __restrict__ scanArr,
                        const int* __restrict__ scal, float* __restrict__ uli,
                        float* __restrict__ ulinv) {
    int i = blockIdx.x * blockDim.x + threadIdx.x;
    if (i >= BN) return;
    uli[i] = (float)scanArr[pfirst[i]];
    if (i >= scal[2]) ulinv[i] = (float)BN;
}

// Stable partition per batch (== stable argsort(-mask)[:T]) and gather outputs
__global__ void k_select(const float* __restrict__ x, const int* __restrict__ pfirst,
                         const int* __restrict__ scanArr, const int* __restrict__ scal,
                         float* __restrict__ ysel, float* __restrict__ idxout,
                         float* __restrict__ msel) {
    int i = blockIdx.x * blockDim.x + threadIdx.x;
    if (i >= BN) return;
    int b = i >> 17;
    int j = i & (NN - 1);
    int base = scanArr[b << 17];
    int ones_before = scanArr[i] - base;
    int cnt1 = ((b == BB - 1) ? scal[2] : scanArr[(b + 1) << 17]) - base;
    int flag = (pfirst[i] == i);
    int pos = flag ? ones_before : cnt1 + (j - ones_before);
    if (pos < TT) {
        float y0 = CELL * rintf(x[3 * i + 0] / CELL);
        float y1 = CELL * rintf(x[3 * i + 1] / CELL);
        float y2 = CELL * rintf(x[3 * i + 2] / CELL);
        int yo = (b * TT + pos) * 3;
        ysel[yo + 0] = y0;
        ysel[yo + 1] = y1;
        ysel[yo + 2] = y2;
        int io = (b * TT + pos) * 2;
        idxout[io + 0] = (float)b;
        idxout[io + 1] = (float)j;
        msel[b * TT + pos] = flag ? 1.0f : 0.0f;
    }
}

extern "C" void kernel_launch(void* const* d_in, const int* in_sizes, int n_in,
                              void* d_out, int out_size, void* d_ws, size_t ws_size,
                              hipStream_t stream) {
    const float* x = (const float*)d_in[0];
    float* out = (float*)d_out;
    char* ws = (char*)d_ws;

    // ws layout (bytes): scalars 256 | slotArr BN*4 | pfirst BN*4 | scanArr BN*4
    //                    | bsums 4096 | hkeys HSIZE*4 | hmin HSIZE*4  => ~112 MB
    int* scal    = (int*)ws;
    int* slotArr = (int*)(ws + 256);
    int* pfirst  = slotArr + BN;
    int* scanArr = pfirst + BN;
    int* bsums   = scanArr + BN;
    int* hkeys   = bsums + 1024;
    int* hmin    = hkeys + HSIZE;

    hipMemsetAsync(hkeys, 0xFF, (size_t)HSIZE * 4, stream);  // all -1 (empty)
    hipMemsetAsync(hmin, 0x7F, (size_t)HSIZE * 4, stream);   // 0x7F7F7F7F > BN
    k_init<<<1, 1, 0, stream>>>(scal);
    k_minmax<<<1024, 256, 0, stream>>>(x, scal);
    k_insert<<<BN / 256, 256, 0, stream>>>(x, scal, hkeys, hmin, slotArr);
    k_scanA<<<SCAN_NBLK, SCAN_TPB, 0, stream>>>(slotArr, hmin, pfirst, bsums);
    k_scanB<<<1, 1024, 0, stream>>>(bsums, scal, SCAN_NBLK);
    k_scanC<<<SCAN_NBLK, SCAN_TPB, 0, stream>>>(pfirst, bsums, scanArr, out + ULV_OFF);
    k_final<<<BN / 256, 256, 0, stream>>>(pfirst, scanArr, scal, out + ULI_OFF, out + ULV_OFF);
    k_select<<<BN / 256, 256, 0, stream>>>(x, pfirst, scanArr, scal,
                                           out + Y_OFF, out + IDX_OFF, out + MSK_OFF);
}

// Round 2
// 539.973 us; speedup vs baseline: 1.2387x; 1.2387x over previous
//
#include <hip/hip_runtime.h>
#include <stdint.h>

// Problem constants (fixed by reference setup_inputs)
#define BB 32
#define NN 131072            // 2^17
#define BN (BB * NN)         // 4,194,304 = 2^22
#define TT 32768             // NUM_POINTS_TARGET
#define CELL 0.05f
#define HBITS 23
#define HSIZE (1 << HBITS)   // 8,388,608 slots
#define HMASK (HSIZE - 1)
#define EMPTY64 0xFFFFFFFFFFFFFFFFULL
#define IDXMASK 0x3FFFFFULL  // low 22 bits = point index

// Output layout in d_out (floats), in return order:
// y_sel [32,32768,3], idx_out [32,32768,2], mask_sel [32,32768],
// ul_idx [BN], ul_idx_inv [BN]
#define Y_OFF   0
#define IDX_OFF (BB * TT * 3)                    // 3,145,728
#define MSK_OFF (IDX_OFF + BB * TT * 2)          // 5,242,880
#define ULI_OFF (MSK_OFF + BB * TT)              // 6,291,456
#define ULV_OFF (ULI_OFF + BN)                   // 10,485,760

#define SCAN_TPB 256
#define SCAN_EPT 16
#define SCAN_EPB (SCAN_TPB * SCAN_EPT)           // 4096
#define SCAN_NBLK (BN / SCAN_EPB)                // 1024

__global__ void k_init(int* scal) {
    scal[0] = 0x7FFFFFFF;  // min
    scal[1] = 0x80000000;  // max
    scal[2] = 0;           // total uniques
}

// Global min/max over all 3*BN quantized coords
__global__ void k_minmax(const float* __restrict__ x, int* scal) {
    int tid = blockIdx.x * blockDim.x + threadIdx.x;
    int stride = gridDim.x * blockDim.x;
    int lmin = 0x7FFFFFFF, lmax = (int)0x80000000;
    for (int i = tid; i < 3 * BN; i += stride) {
        int g = (int)rintf(x[i] / CELL);   // round half-to-even like jnp.round
        lmin = min(lmin, g);
        lmax = max(lmax, g);
    }
    for (int off = 32; off > 0; off >>= 1) {
        lmin = min(lmin, __shfl_down(lmin, off));
        lmax = max(lmax, __shfl_down(lmax, off));
    }
    if ((threadIdx.x & 63) == 0) {
        atomicMin(&scal[0], lmin);
        atomicMax(&scal[1], lmax);
    }
}

// Voxel key per point; insert into packed 64-bit hash:
// slot = (key << 22) | min_flat_idx. One random line per point.
__global__ void k_insert(const float* __restrict__ x, const int* __restrict__ scal,
                         unsigned long long* __restrict__ slots,
                         int* __restrict__ slotArr) {
    int i = blockIdx.x * blockDim.x + threadIdx.x;
    if (i >= BN) return;
    int ming = scal[0];
    int gs = scal[1] - ming + 2;
    int g0 = (int)rintf(x[3 * i + 0] / CELL) - ming;
    int g1 = (int)rintf(x[3 * i + 1] / CELL) - ming;
    int g2 = (int)rintf(x[3 * i + 2] / CELL) - ming;
    int b = i >> 17;  // i / NN
    unsigned int key = (unsigned int)(gs * (gs * g0 + g1) + g2 + gs * gs * gs * b); // <2^29
    unsigned long long packed = ((unsigned long long)key << 22) | (unsigned int)i;
    unsigned int s = (key * 2654435761u) >> (32 - HBITS);
    for (;;) {
        unsigned long long cur = slots[s];
        if (cur != EMPTY64) {
            if ((unsigned int)(cur >> 22) == key) {
                atomicMin(&slots[s], packed);   // same key: min over idx
                break;
            }
            s = (s + 1) & HMASK;
            continue;
        }
        unsigned long long old = atomicCAS(&slots[s], EMPTY64, packed);
        if (old == EMPTY64) break;              // claimed fresh slot
        if ((unsigned int)(old >> 22) == key) { // lost race to same key
            atomicMin(&slots[s], packed);
            break;
        }
        s = (s + 1) & HMASK;                    // lost to different key
    }
    slotArr[i] = (int)s;
}

// Scan pass A: resolve first-occurrence position per point; block partial sums of flags
__global__ void k_scanA(const int* __restrict__ slotArr,
                        const unsigned long long* __restrict__ slots,
                        int* __restrict__ pfirst, int* __restrict__ bsums) {
    int t = threadIdx.x;
    int base = blockIdx.x * SCAN_EPB + t * SCAN_EPT;
    int s = 0;
    for (int e = 0; e < SCAN_EPT; e++) {
        int i = base + e;
        int p = (int)(slots[slotArr[i]] & IDXMASK);
        pfirst[i] = p;
        s += (p == i);
    }
    __shared__ int sh[SCAN_TPB];
    sh[t] = s;
    __syncthreads();
    for (int off = SCAN_TPB / 2; off > 0; off >>= 1) {
        if (t < off) sh[t] += sh[t + off];
        __syncthreads();
    }
    if (t == 0) bsums[blockIdx.x] = sh[0];
}

// Scan pass B: exclusive scan of 1024 block sums; store grand total
__global__ void k_scanB(int* __restrict__ bsums, int* __restrict__ scal, int nb) {
    __shared__ int sh[1024];
    int t = threadIdx.x;
    int v = (t < nb) ? bsums[t] : 0;
    sh[t] = v;
    __syncthreads();
    for (int off = 1; off < 1024; off <<= 1) {
        int add = (t >= off) ? sh[t - off] : 0;
        __syncthreads();
        sh[t] += add;
        __syncthreads();
    }
    if (t < nb) bsums[t] = sh[t] - v;       // exclusive
    if (t == nb - 1) scal[2] = sh[t];       // total uniques U
}

// Scan pass C: write exclusive scan per element; scatter ul_idx_inv[rank] = pos
__global__ void k_scanC(const int* __restrict__ pfirst, const int* __restrict__ bsums,
                        int* __restrict__ scanArr, float* __restrict__ ulinv) {
    int t = threadIdx.x;
    int base = blockIdx.x * SCAN_EPB + t * SCAN_EPT;
    int flags[SCAN_EPT];
    int s = 0;
    for (int e = 0; e < SCAN_EPT; e++) {
        int i = base + e;
        int p = pfirst[i];
        flags[e] = (p == i) ? 1 : 0;
        s += flags[e];
    }
    __shared__ int sh[SCAN_TPB];
    sh[t] = s;
    __syncthreads();
    int v = s;
    for (int off = 1; off < SCAN_TPB; off <<= 1) {
        int add = (t >= off) ? sh[t - off] : 0;
        __syncthreads();
        sh[t] += add;
        __syncthreads();
    }
    int prefix = bsums[blockIdx.x] + sh[t] - v;  // exclusive prefix for this thread
    for (int e = 0; e < SCAN_EPT; e++) {
        int i = base + e;
        scanArr[i] = prefix;
        if (flags[e]) ulinv[prefix] = (float)i;
        prefix += flags[e];
    }
}

// Fused: ul_idx gather + ul_idx_inv tail pad + stable top-k partition + output gather
__global__ void k_select(const float* __restrict__ x, const int* __restrict__ pfirst,
                         const int* __restrict__ scanArr, const int* __restrict__ scal,
                         float* __restrict__ ysel, float* __restrict__ idxout,
                         float* __restrict__ msel, float* __restrict__ uli,
                         float* __restrict__ ulinv) {
    int i = blockIdx.x * blockDim.x + threadIdx.x;
    if (i >= BN) return;
    int p = pfirst[i];
    uli[i] = (float)scanArr[p];              // appearance rank of i's voxel
    int U = scal[2];
    if (i >= U) ulinv[i] = (float)BN;        // sentinel tail
    int b = i >> 17;
    int j = i & (NN - 1);
    int base = scanArr[b << 17];
    int ones_before = scanArr[i] - base;
    int cnt1 = ((b == BB - 1) ? U : scanArr[(b + 1) << 17]) - base;
    int flag = (p == i);
    int pos = flag ? ones_before : cnt1 + (j - ones_before);
    if (pos < TT) {
        float y0 = CELL * rintf(x[3 * i + 0] / CELL);
        float y1 = CELL * rintf(x[3 * i + 1] / CELL);
        float y2 = CELL * rintf(x[3 * i + 2] / CELL);
        int yo = (b * TT + pos) * 3;
        ysel[yo + 0] = y0;
        ysel[yo + 1] = y1;
        ysel[yo + 2] = y2;
        int io = (b * TT + pos) * 2;
        idxout[io + 0] = (float)b;
        idxout[io + 1] = (float)j;
        msel[b * TT + pos] = flag ? 1.0f : 0.0f;
    }
}

extern "C" void kernel_launch(void* const* d_in, const int* in_sizes, int n_in,
                              void* d_out, int out_size, void* d_ws, size_t ws_size,
                              hipStream_t stream) {
    const float* x = (const float*)d_in[0];
    float* out = (float*)d_out;
    char* ws = (char*)d_ws;

    // ws layout (bytes): scalars 256 | slotArr BN*4 | pfirst BN*4 | scanArr BN*4
    //                    | bsums 4096 | slots64 HSIZE*8  => ~115 MB
    int* scal    = (int*)ws;
    int* slotArr = (int*)(ws + 256);
    int* pfirst  = slotArr + BN;
    int* scanArr = pfirst + BN;
    int* bsums   = scanArr + BN;
    unsigned long long* slots = (unsigned long long*)(bsums + 1024);

    hipMemsetAsync(slots, 0xFF, (size_t)HSIZE * 8, stream);  // all EMPTY64
    k_init<<<1, 1, 0, stream>>>(scal);
    k_minmax<<<1024, 256, 0, stream>>>(x, scal);
    k_insert<<<BN / 256, 256, 0, stream>>>(x, scal, slots, slotArr);
    k_scanA<<<SCAN_NBLK, SCAN_TPB, 0, stream>>>(slotArr, slots, pfirst, bsums);
    k_scanB<<<1, 1024, 0, stream>>>(bsums, scal, SCAN_NBLK);
    k_scanC<<<SCAN_NBLK, SCAN_TPB, 0, stream>>>(pfirst, bsums, scanArr, out + ULV_OFF);
    k_select<<<BN / 256, 256, 0, stream>>>(x, pfirst, scanArr, scal,
                                           out + Y_OFF, out + IDX_OFF, out + MSK_OFF,
                                           out + ULI_OFF, out + ULV_OFF);
}